// Round 1
// baseline (543.777 us; speedup 1.0000x reference)
//
#include <hip/hip_runtime.h>
#include <cmath>

typedef unsigned short u16;
typedef short v8s __attribute__((ext_vector_type(8)));
typedef float v4f __attribute__((ext_vector_type(4)));
typedef unsigned short v4u __attribute__((ext_vector_type(4)));

__device__ __forceinline__ u16 f2bf(float f) {
  unsigned u = __builtin_bit_cast(unsigned, f);
  u += 0x7fffu + ((u >> 16) & 1u);
  return (u16)(u >> 16);
}
__device__ __forceinline__ float bf2f(u16 h) {
  unsigned u = ((unsigned)h) << 16;
  return __builtin_bit_cast(float, u);
}

// ---------------- cast fp32 -> bf16 (vectorized, G13) ----------------
__global__ void k_cast_bf16(const float* __restrict__ in, u16* __restrict__ out, int n4) {
  int i = blockIdx.x * blockDim.x + threadIdx.x;
  if (i >= n4) return;
  v4f v = ((const v4f*)in)[i];
  v4u o;
  o[0] = f2bf(v[0]); o[1] = f2bf(v[1]); o[2] = f2bf(v[2]); o[3] = f2bf(v[3]);
  ((v4u*)out)[i] = o;
}

// ---------------- RoPE cos/sin table [S][64] f32 ----------------
__global__ void k_rope_tab(float* __restrict__ cosT, float* __restrict__ sinT, float log2_base) {
  int idx = blockIdx.x * blockDim.x + threadIdx.x;
  int t = idx >> 6, i = idx & 63;
  float inv = exp2f(-(float)i * (1.0f / 64.0f) * log2_base);
  float fr = (float)t * inv;
  cosT[idx] = cosf(fr);
  sinT[idx] = sinf(fr);
}

// ---------------- per-head RMSNorm + RoPE + optional gain (in-place, bf16) ----
// one wave per 128-elem head vector; lane l handles elems l and 64+l
__global__ void k_rmsnorm_rope(u16* __restrict__ qk, const float* __restrict__ cosT,
                               const float* __restrict__ sinT, const float* __restrict__ gain,
                               int H, int S) {
  int row = blockIdx.x * 4 + (threadIdx.x >> 6);
  int l = threadIdx.x & 63;
  int h = row % H;
  int m = row / H;
  int s = m % S;  // m = b*S + s
  u16* p = qk + (size_t)row * 128;
  float a = bf2f(p[l]), b = bf2f(p[64 + l]);
  float ss = a * a + b * b;
#pragma unroll
  for (int o = 32; o; o >>= 1) ss += __shfl_xor(ss, o, 64);
  float r = rsqrtf(ss * (1.0f / 128.0f) + 1.1920929e-7f);  // finfo(f32).eps
  a *= r; b *= r;
  float c = cosT[s * 64 + l], sn = sinT[s * 64 + l];
  float o1 = a * c + b * sn;   // x1*c + x2*s
  float o2 = b * c - a * sn;   // -x1*s + x2*c
  if (gain != nullptr) { float g = gain[h]; o1 *= g; o2 *= g; }
  p[l] = f2bf(o1);
  p[64 + l] = f2bf(o2);
}

// ---------------- bf16 GEMM: C[M,N] = A[M,K] * Bw[N,K]^T ----------------
// 128x128 tile, BK=32, 4 waves (2x2), global_load_lds width-16 staging (m97 structure)
template <typename OUT_T, bool TRANS>
__global__ __launch_bounds__(256) void k_gemm_bt(const u16* __restrict__ A,
                                                 const u16* __restrict__ Bw,
                                                 OUT_T* __restrict__ C, int M, int N, int K) {
  __shared__ u16 sA[128 * 32];
  __shared__ u16 sB[128 * 32];
  const int tid = threadIdx.x;
  const int w = tid >> 6, l = tid & 63;
  const int lr = l & 15, lh = l >> 4;
  const int wr = w >> 1, wc = w & 1;
  const int row0 = blockIdx.y * 128, col0 = blockIdx.x * 128;
  v4f zz = {0.f, 0.f, 0.f, 0.f};
  v4f acc[4][4];
#pragma unroll
  for (int mi = 0; mi < 4; ++mi)
#pragma unroll
    for (int ni = 0; ni < 4; ++ni) acc[mi][ni] = zz;

  const int lrow = l >> 2;       // 0..15 within 16-row chunk
  const int lcol = (l & 3) * 8;  // 0,8,16,24

  for (int k0 = 0; k0 < K; k0 += 32) {
#pragma unroll
    for (int i = 0; i < 2; ++i) {
      int c = i * 4 + w;  // chunk 0..7, wave-uniform
      const u16* srcA = A + (size_t)(row0 + c * 16 + lrow) * K + (k0 + lcol);
      const u16* srcB = Bw + (size_t)(col0 + c * 16 + lrow) * K + (k0 + lcol);
      __builtin_amdgcn_global_load_lds((const __attribute__((address_space(1))) void*)srcA,
                                       (__attribute__((address_space(3))) void*)(sA + c * 512),
                                       16, 0, 0);
      __builtin_amdgcn_global_load_lds((const __attribute__((address_space(1))) void*)srcB,
                                       (__attribute__((address_space(3))) void*)(sB + c * 512),
                                       16, 0, 0);
    }
    __syncthreads();  // drains vmcnt -> LDS visible
    v8s af[4], bfr[4];
#pragma unroll
    for (int mi = 0; mi < 4; ++mi)
      af[mi] = *(const v8s*)(sA + (wr * 64 + mi * 16 + lr) * 32 + lh * 8);
#pragma unroll
    for (int ni = 0; ni < 4; ++ni)
      bfr[ni] = *(const v8s*)(sB + (wc * 64 + ni * 16 + lr) * 32 + lh * 8);
#pragma unroll
    for (int mi = 0; mi < 4; ++mi)
#pragma unroll
      for (int ni = 0; ni < 4; ++ni)
        acc[mi][ni] = __builtin_amdgcn_mfma_f32_16x16x32_bf16(af[mi], bfr[ni], acc[mi][ni], 0, 0, 0);
    __syncthreads();
  }
  // epilogue: C/D layout col=lane&15, row=(lane>>4)*4+reg (m89-verified)
#pragma unroll
  for (int mi = 0; mi < 4; ++mi) {
#pragma unroll
    for (int ni = 0; ni < 4; ++ni) {
      int row = row0 + wr * 64 + mi * 16 + lh * 4;
      int col = col0 + wc * 64 + ni * 16 + lr;
#pragma unroll
      for (int r = 0; r < 4; ++r) {
        float v = acc[mi][ni][r];
        if constexpr (TRANS) {
          if constexpr (sizeof(OUT_T) == 2) C[(size_t)col * M + row + r] = (OUT_T)f2bf(v);
          else                              C[(size_t)col * M + row + r] = (OUT_T)v;
        } else {
          if constexpr (sizeof(OUT_T) == 2) C[(size_t)(row + r) * N + col] = (OUT_T)f2bf(v);
          else                              C[(size_t)(row + r) * N + col] = (OUT_T)v;
        }
      }
    }
  }
}

// ---------------- causal GQA flash attention ----------------
// grid (B*H, S/64), 256 thr = 4 independent waves, 16 q-rows each. No barriers.
// Q[m][h*128+d], K[m][kvh*128+d], Vt[kvh*128+d][m] (transposed), O[m][h*128+d]
__global__ __launch_bounds__(256) void k_flash_attn(const u16* __restrict__ Q,
                                                    const u16* __restrict__ Kb,
                                                    const u16* __restrict__ Vt,
                                                    u16* __restrict__ O, int S, int H, int KH,
                                                    int Mtot) {
  const int bh = blockIdx.x, qt = blockIdx.y;
  const int h = bh % H, b = bh / H;
  const int kvh = h / (H / KH);
  const int w = threadIdx.x >> 6, l = threadIdx.x & 63;
  const int lr = l & 15, lh = l >> 4;
  const int q0 = qt * 64;
  __shared__ u16 P_lds[4][16 * 72];  // per-wave, padded (stride 144B: 2-way free)
  u16* pl = P_lds[w];

  const float SL2E = 1.44269504088896340f / sqrtf(128.0f);  // log2(e)/sqrt(hd)
  v4f zz = {0.f, 0.f, 0.f, 0.f};

  // Q fragments (A-operand: row = l%16, k = 8*(l/16)+j + 32c), kept in regs
  v8s qf[4];
  const u16* qp = Q + (size_t)(b * S + q0 + w * 16 + lr) * (size_t)(H * 128) + h * 128 + lh * 8;
#pragma unroll
  for (int c = 0; c < 4; ++c) qf[c] = *(const v8s*)(qp + c * 32);

  v4f o_acc[8];
#pragma unroll
  for (int df = 0; df < 8; ++df) o_acc[df] = zz;
  float m_run[4] = {-1e30f, -1e30f, -1e30f, -1e30f};
  float l_run[4] = {0.f, 0.f, 0.f, 0.f};

  const int strideK = KH * 128;
  const u16* Kbase = Kb + (size_t)b * S * strideK + kvh * 128;
  const u16* Vbase = Vt + (size_t)(kvh * 128) * Mtot + (size_t)b * S;

  const int ntiles = qt + 1;  // causal tile skip
  for (int t = 0; t < ntiles; ++t) {
    const int kv0 = t * 64;
    const bool lastTile = (t == ntiles - 1);
    // S = Q * K^T : B-operand n-col = kv (l&15), k contiguous per lane -> direct global 16B
    v4f sv[4];
#pragma unroll
    for (int nf = 0; nf < 4; ++nf) {
      v4f a_ = zz;
      const u16* kp = Kbase + (size_t)(kv0 + nf * 16 + lr) * strideK + lh * 8;
#pragma unroll
      for (int c = 0; c < 4; ++c) {
        v8s kf = *(const v8s*)(kp + c * 32);
        a_ = __builtin_amdgcn_mfma_f32_16x16x32_bf16(qf[c], kf, a_, 0, 0, 0);
      }
      sv[nf] = a_;
    }
    // scale(+log2e fold) + causal mask + online softmax per 16-lane row group
    float p[4][4];
#pragma unroll
    for (int r = 0; r < 4; ++r) {
      const int qi = q0 + w * 16 + lh * 4 + r;
      float vmax = -1e30f;
#pragma unroll
      for (int nf = 0; nf < 4; ++nf) {
        float s_ = sv[nf][r] * SL2E;
        if (lastTile && (kv0 + nf * 16 + lr) > qi) s_ = -1e30f;
        sv[nf][r] = s_;
        vmax = fmaxf(vmax, s_);
      }
#pragma unroll
      for (int o = 1; o < 16; o <<= 1) vmax = fmaxf(vmax, __shfl_xor(vmax, o, 16));
      float mnew = fmaxf(m_run[r], vmax);
      float corr = exp2f(m_run[r] - mnew);
      float rsum = 0.f;
#pragma unroll
      for (int nf = 0; nf < 4; ++nf) {
        float pv = exp2f(sv[nf][r] - mnew);
        p[nf][r] = pv;
        rsum += pv;
      }
#pragma unroll
      for (int o = 1; o < 16; o <<= 1) rsum += __shfl_xor(rsum, o, 16);
      l_run[r] = l_run[r] * corr + rsum;
      m_run[r] = mnew;
#pragma unroll
      for (int df = 0; df < 8; ++df) o_acc[df][r] *= corr;
    }
    // P (C-layout) -> per-wave LDS -> reload in A-layout
#pragma unroll
    for (int nf = 0; nf < 4; ++nf)
#pragma unroll
      for (int r = 0; r < 4; ++r)
        pl[(lh * 4 + r) * 72 + nf * 16 + lr] = f2bf(p[nf][r]);
    asm volatile("s_waitcnt lgkmcnt(0)" ::: "memory");
    __builtin_amdgcn_sched_barrier(0);  // rule 18
    v8s ap[2];
#pragma unroll
    for (int c2 = 0; c2 < 2; ++c2) ap[c2] = *(const v8s*)(pl + lr * 72 + c2 * 32 + lh * 8);
    // O += P * V : V from transposed v_t, per-lane contiguous 16B
#pragma unroll
    for (int df = 0; df < 8; ++df) {
      const u16* vp = Vbase + (size_t)(df * 16 + lr) * Mtot + kv0 + lh * 8;
#pragma unroll
      for (int c2 = 0; c2 < 2; ++c2) {
        v8s vf = *(const v8s*)(vp + c2 * 32);
        o_acc[df] = __builtin_amdgcn_mfma_f32_16x16x32_bf16(ap[c2], vf, o_acc[df], 0, 0, 0);
      }
    }
  }
  // epilogue: normalize and store bf16
  u16* op = O + (size_t)(b * S + q0 + w * 16 + lh * 4) * (size_t)(H * 128) + h * 128;
#pragma unroll
  for (int r = 0; r < 4; ++r) {
    float inv = 1.0f / l_run[r];
#pragma unroll
    for (int df = 0; df < 8; ++df)
      op[(size_t)r * (H * 128) + df * 16 + lr] = f2bf(o_acc[df][r] * inv);
  }
}

extern "C" void kernel_launch(void* const* d_in, const int* in_sizes, int n_in, void* d_out,
                              int out_size, void* d_ws, size_t ws_size, hipStream_t stream) {
  const float* x = (const float*)d_in[0];
  const float* Wq = (const float*)d_in[1];
  const float* Wk = (const float*)d_in[2];
  const float* Wv = (const float*)d_in[3];
  const float* Wp = (const float*)d_in[4];
  const float* gain = (const float*)d_in[5];
  float* out = (float*)d_out;

  const int B = 2, S = 2048, D = 2048, H = 16, KH = 4;
  const int M = B * S;       // 4096
  const int KVD = KH * 128;  // 512

  char* w = (char*)d_ws;
  u16* x_bf = (u16*)w;  w += (size_t)M * D * 2;
  u16* wq_bf = (u16*)w; w += (size_t)D * D * 2;
  u16* wk_bf = (u16*)w; w += (size_t)KVD * D * 2;
  u16* wv_bf = (u16*)w; w += (size_t)KVD * D * 2;
  u16* wp_bf = (u16*)w; w += (size_t)D * D * 2;
  u16* q_bf = (u16*)w;  w += (size_t)M * D * 2;
  u16* k_bf = (u16*)w;  w += (size_t)M * KVD * 2;
  u16* v_t = (u16*)w;   w += (size_t)M * KVD * 2;
  u16* ao_bf = (u16*)w; w += (size_t)M * D * 2;
  float* cosT = (float*)w; w += (size_t)S * 64 * 4;
  float* sinT = (float*)w; w += (size_t)S * 64 * 4;
  if ((size_t)(w - (char*)d_ws) > ws_size) return;  // ws too small: fail loudly

  k_cast_bf16<<<(M * D / 4 + 255) / 256, 256, 0, stream>>>(x, x_bf, M * D / 4);
  k_cast_bf16<<<(D * D / 4 + 255) / 256, 256, 0, stream>>>(Wq, wq_bf, D * D / 4);
  k_cast_bf16<<<(KVD * D / 4 + 255) / 256, 256, 0, stream>>>(Wk, wk_bf, KVD * D / 4);
  k_cast_bf16<<<(KVD * D / 4 + 255) / 256, 256, 0, stream>>>(Wv, wv_bf, KVD * D / 4);
  k_cast_bf16<<<(D * D / 4 + 255) / 256, 256, 0, stream>>>(Wp, wp_bf, D * D / 4);

  double scale = (double)S / 1024.0;
  double base = (S > 1024) ? 10000.0 * pow(scale, 128.0 / 126.0) : 10000.0;
  float l2b = (float)(log(base) / log(2.0));
  k_rope_tab<<<S * 64 / 256, 256, 0, stream>>>(cosT, sinT, l2b);

  dim3 blk(256);
  dim3 gq(D / 128, M / 128);
  k_gemm_bt<u16, false><<<gq, blk, 0, stream>>>(x_bf, wq_bf, q_bf, M, D, D);
  dim3 gkv(KVD / 128, M / 128);
  k_gemm_bt<u16, false><<<gkv, blk, 0, stream>>>(x_bf, wk_bf, k_bf, M, KVD, D);
  k_gemm_bt<u16, true><<<gkv, blk, 0, stream>>>(x_bf, wv_bf, v_t, M, KVD, D);

  k_rmsnorm_rope<<<(M * H) / 4, 256, 0, stream>>>(q_bf, cosT, sinT, gain, H, S);
  k_rmsnorm_rope<<<(M * KH) / 4, 256, 0, stream>>>(k_bf, cosT, sinT, nullptr, KH, S);

  dim3 ga(B * H, S / 64);
  k_flash_attn<<<ga, blk, 0, stream>>>(q_bf, k_bf, v_t, ao_bf, S, H, KH, M);

  k_gemm_bt<float, false><<<gq, blk, 0, stream>>>(ao_bf, wp_bf, out, M, D, D);
}

// Round 2
// 411.073 us; speedup vs baseline: 1.3228x; 1.3228x over previous
//
#include <hip/hip_runtime.h>
#include <cmath>

typedef unsigned short u16;
typedef short v8s __attribute__((ext_vector_type(8)));
typedef float v4f __attribute__((ext_vector_type(4)));
typedef unsigned short v4u __attribute__((ext_vector_type(4)));

__device__ __forceinline__ u16 f2bf(float f) {
  unsigned u = __builtin_bit_cast(unsigned, f);
  u += 0x7fffu + ((u >> 16) & 1u);
  return (u16)(u >> 16);
}
__device__ __forceinline__ float bf2f(u16 h) {
  unsigned u = ((unsigned)h) << 16;
  return __builtin_bit_cast(float, u);
}

// ---------------- cast fp32 -> bf16 (vectorized, G13) ----------------
__global__ void k_cast_bf16(const float* __restrict__ in, u16* __restrict__ out, int n4) {
  int i = blockIdx.x * blockDim.x + threadIdx.x;
  if (i >= n4) return;
  v4f v = ((const v4f*)in)[i];
  v4u o;
  o[0] = f2bf(v[0]); o[1] = f2bf(v[1]); o[2] = f2bf(v[2]); o[3] = f2bf(v[3]);
  ((v4u*)out)[i] = o;
}

// ---------------- RoPE cos/sin table [S][64] f32 ----------------
__global__ void k_rope_tab(float* __restrict__ cosT, float* __restrict__ sinT, float log2_base) {
  int idx = blockIdx.x * blockDim.x + threadIdx.x;
  int t = idx >> 6, i = idx & 63;
  float inv = exp2f(-(float)i * (1.0f / 64.0f) * log2_base);
  float fr = (float)t * inv;
  cosT[idx] = cosf(fr);
  sinT[idx] = sinf(fr);
}

// ---------------- per-head RMSNorm + RoPE + optional gain (in-place, bf16) ----
__global__ void k_rmsnorm_rope(u16* __restrict__ qk, const float* __restrict__ cosT,
                               const float* __restrict__ sinT, const float* __restrict__ gain,
                               int H, int S) {
  int row = blockIdx.x * 4 + (threadIdx.x >> 6);
  int l = threadIdx.x & 63;
  int h = row % H;
  int m = row / H;
  int s = m % S;
  u16* p = qk + (size_t)row * 128;
  float a = bf2f(p[l]), b = bf2f(p[64 + l]);
  float ss = a * a + b * b;
#pragma unroll
  for (int o = 32; o; o >>= 1) ss += __shfl_xor(ss, o, 64);
  float r = rsqrtf(ss * (1.0f / 128.0f) + 1.1920929e-7f);
  a *= r; b *= r;
  float c = cosT[s * 64 + l], sn = sinT[s * 64 + l];
  float o1 = a * c + b * sn;
  float o2 = b * c - a * sn;
  if (gain != nullptr) { float g = gain[h]; o1 *= g; o2 *= g; }
  p[l] = f2bf(o1);
  p[64 + l] = f2bf(o2);
}

// ---------------- bf16 GEMM: C[M,N] = A[M,K] * Bw[N,K]^T (m97 structure) ------
template <typename OUT_T, bool TRANS>
__global__ __launch_bounds__(256) void k_gemm_bt(const u16* __restrict__ A,
                                                 const u16* __restrict__ Bw,
                                                 OUT_T* __restrict__ C, int M, int N, int K) {
  __shared__ u16 sA[128 * 32];
  __shared__ u16 sB[128 * 32];
  const int tid = threadIdx.x;
  const int w = tid >> 6, l = tid & 63;
  const int lr = l & 15, lh = l >> 4;
  const int wr = w >> 1, wc = w & 1;
  const int row0 = blockIdx.y * 128, col0 = blockIdx.x * 128;
  v4f zz = {0.f, 0.f, 0.f, 0.f};
  v4f acc[4][4];
#pragma unroll
  for (int mi = 0; mi < 4; ++mi)
#pragma unroll
    for (int ni = 0; ni < 4; ++ni) acc[mi][ni] = zz;

  const int lrow = l >> 2;
  const int lcol = (l & 3) * 8;

  for (int k0 = 0; k0 < K; k0 += 32) {
#pragma unroll
    for (int i = 0; i < 2; ++i) {
      int c = i * 4 + w;
      const u16* srcA = A + (size_t)(row0 + c * 16 + lrow) * K + (k0 + lcol);
      const u16* srcB = Bw + (size_t)(col0 + c * 16 + lrow) * K + (k0 + lcol);
      __builtin_amdgcn_global_load_lds((const __attribute__((address_space(1))) void*)srcA,
                                       (__attribute__((address_space(3))) void*)(sA + c * 512),
                                       16, 0, 0);
      __builtin_amdgcn_global_load_lds((const __attribute__((address_space(1))) void*)srcB,
                                       (__attribute__((address_space(3))) void*)(sB + c * 512),
                                       16, 0, 0);
    }
    __syncthreads();
    v8s af[4], bfr[4];
#pragma unroll
    for (int mi = 0; mi < 4; ++mi)
      af[mi] = *(const v8s*)(sA + (wr * 64 + mi * 16 + lr) * 32 + lh * 8);
#pragma unroll
    for (int ni = 0; ni < 4; ++ni)
      bfr[ni] = *(const v8s*)(sB + (wc * 64 + ni * 16 + lr) * 32 + lh * 8);
#pragma unroll
    for (int mi = 0; mi < 4; ++mi)
#pragma unroll
      for (int ni = 0; ni < 4; ++ni)
        acc[mi][ni] = __builtin_amdgcn_mfma_f32_16x16x32_bf16(af[mi], bfr[ni], acc[mi][ni], 0, 0, 0);
    __syncthreads();
  }
#pragma unroll
  for (int mi = 0; mi < 4; ++mi) {
#pragma unroll
    for (int ni = 0; ni < 4; ++ni) {
      int row = row0 + wr * 64 + mi * 16 + lh * 4;
      int col = col0 + wc * 64 + ni * 16 + lr;
#pragma unroll
      for (int r = 0; r < 4; ++r) {
        float v = acc[mi][ni][r];
        if constexpr (TRANS) {
          if constexpr (sizeof(OUT_T) == 2) C[(size_t)col * M + row + r] = (OUT_T)f2bf(v);
          else                              C[(size_t)col * M + row + r] = (OUT_T)v;
        } else {
          if constexpr (sizeof(OUT_T) == 2) C[(size_t)(row + r) * N + col] = (OUT_T)f2bf(v);
          else                              C[(size_t)(row + r) * N + col] = (OUT_T)v;
        }
      }
    }
  }
}

// ---------------- causal GQA flash attention v2 ----------------
// grid (B*H, 16): each block does q-tiles {y, 31-y} (33 tile-units -> balanced).
// 4 waves x 16 q-rows. K tile staged to LDS (double-buffered, G21 swizzle);
// V prefetched to regs before softmax; P via per-wave padded LDS.
__global__ __launch_bounds__(256) void k_flash_attn(const u16* __restrict__ Q,
                                                    const u16* __restrict__ Kb,
                                                    const u16* __restrict__ Vt,
                                                    u16* __restrict__ O, int S, int H, int KH,
                                                    int Mtot) {
  const int bh = blockIdx.x;
  const int h = bh % H, b = bh / H;
  const int kvh = h / (H / KH);
  const int w = threadIdx.x >> 6, l = threadIdx.x & 63;
  const int lr = l & 15, lh = l >> 4;

  __shared__ alignas(16) char sK[2][16384];  // 64 kv-rows x 256B, swizzled
  __shared__ u16 P_lds[4][16 * 72];
  u16* pl = P_lds[w];

  const float SL2E = 1.44269504088896340f / sqrtf(128.0f);
  v4f zz = {0.f, 0.f, 0.f, 0.f};
  const int strideK = KH * 128;
  const int strideKB = strideK * 2;
  const char* KheadB = (const char*)Kb + 2 * ((size_t)b * S * strideK + (size_t)kvh * 128);
  const u16* Vbase = Vt + (size_t)(kvh * 128) * Mtot + (size_t)b * S;

  for (int pp = 0; pp < 2; ++pp) {
    const int qt = (pp == 0) ? (int)blockIdx.y : (S / 64 - 1 - (int)blockIdx.y);
    const int q0 = qt * 64;
    const int nt = qt + 1;

    // Q fragments in regs
    v8s qf[4];
    const u16* qp = Q + (size_t)(b * S + q0 + w * 16 + lr) * (size_t)(H * 128) + h * 128 + lh * 8;
#pragma unroll
    for (int c = 0; c < 4; ++c) qf[c] = *(const v8s*)(qp + c * 32);

    v4f o_acc[8];
#pragma unroll
    for (int df = 0; df < 8; ++df) o_acc[df] = zz;
    float m_run[4] = {-1e30f, -1e30f, -1e30f, -1e30f};
    float l_run[4] = {0.f, 0.f, 0.f, 0.f};

    // prologue: stage K tile 0 into buf 0 (16 chunk-issues, 4 per wave)
    {
      const char* Kt = KheadB;  // kv0 = 0
#pragma unroll
      for (int j = 0; j < 4; ++j) {
        int jj = w * 4 + j;
        int ci = jj * 64 + l;
        int r = ci >> 4;
        int bc = (ci & 15) << 4;
        const char* src = Kt + (size_t)r * strideKB + (bc ^ ((r & 15) << 4));
        __builtin_amdgcn_global_load_lds((const __attribute__((address_space(1))) void*)src,
                                         (__attribute__((address_space(3))) void*)(sK[0] + jj * 1024),
                                         16, 0, 0);
      }
    }
    __syncthreads();

    int buf = 0;
    for (int t = 0; t < nt; ++t) {
      const int kv0 = t * 64;
      const bool lastTile = (t == nt - 1);
      const char* sKb = sK[buf];

      // ---- QK^T from LDS (swizzled reads, ~4-way residual) ----
      v4f sv[4];
#pragma unroll
      for (int nf = 0; nf < 4; ++nf) {
        v4f a_ = zz;
        const int r = nf * 16 + lr;
#pragma unroll
        for (int c = 0; c < 4; ++c) {
          v8s kf = *(const v8s*)(sKb + r * 256 + ((lh * 16 + c * 64) ^ (lr << 4)));
          a_ = __builtin_amdgcn_mfma_f32_16x16x32_bf16(qf[c], kf, a_, 0, 0, 0);
        }
        sv[nf] = a_;
      }

      // ---- prefetch V fragments to regs (latency hides under softmax) ----
      v8s vf[8][2];
#pragma unroll
      for (int df = 0; df < 8; ++df) {
        const u16* vp = Vbase + (size_t)(df * 16 + lr) * Mtot + kv0 + lh * 8;
#pragma unroll
        for (int c2 = 0; c2 < 2; ++c2) vf[df][c2] = *(const v8s*)(vp + c2 * 32);
      }

      // ---- stage next K tile into other buffer ----
      if (t + 1 < nt) {
        const char* Kt = KheadB + (size_t)(kv0 + 64) * strideKB;
        char* dst = (char*)sK[buf ^ 1];
#pragma unroll
        for (int j = 0; j < 4; ++j) {
          int jj = w * 4 + j;
          int ci = jj * 64 + l;
          int r = ci >> 4;
          int bc = (ci & 15) << 4;
          const char* src = Kt + (size_t)r * strideKB + (bc ^ ((r & 15) << 4));
          __builtin_amdgcn_global_load_lds((const __attribute__((address_space(1))) void*)src,
                                           (__attribute__((address_space(3))) void*)(dst + jj * 1024),
                                           16, 0, 0);
        }
      }

      // ---- online softmax (per 16-lane row group) ----
      float p[4][4];
#pragma unroll
      for (int r = 0; r < 4; ++r) {
        const int qi = q0 + w * 16 + lh * 4 + r;
        float vmax = -1e30f;
#pragma unroll
        for (int nf = 0; nf < 4; ++nf) {
          float s_ = sv[nf][r] * SL2E;
          if (lastTile && (kv0 + nf * 16 + lr) > qi) s_ = -1e30f;
          sv[nf][r] = s_;
          vmax = fmaxf(vmax, s_);
        }
#pragma unroll
        for (int o = 1; o < 16; o <<= 1) vmax = fmaxf(vmax, __shfl_xor(vmax, o, 16));
        float mnew = fmaxf(m_run[r], vmax);
        float corr = exp2f(m_run[r] - mnew);
        float rsum = 0.f;
#pragma unroll
        for (int nf = 0; nf < 4; ++nf) {
          float pv = exp2f(sv[nf][r] - mnew);
          p[nf][r] = pv;
          rsum += pv;
        }
#pragma unroll
        for (int o = 1; o < 16; o <<= 1) rsum += __shfl_xor(rsum, o, 16);
        l_run[r] = l_run[r] * corr + rsum;
        m_run[r] = mnew;
#pragma unroll
        for (int df = 0; df < 8; ++df) o_acc[df][r] *= corr;
      }

      // ---- P (C-layout) -> per-wave LDS -> A-layout ----
#pragma unroll
      for (int nf = 0; nf < 4; ++nf)
#pragma unroll
        for (int r = 0; r < 4; ++r)
          pl[(lh * 4 + r) * 72 + nf * 16 + lr] = f2bf(p[nf][r]);
      asm volatile("s_waitcnt lgkmcnt(0)" ::: "memory");
      __builtin_amdgcn_sched_barrier(0);  // rule 18
      v8s ap[2];
#pragma unroll
      for (int c2 = 0; c2 < 2; ++c2) ap[c2] = *(const v8s*)(pl + lr * 72 + c2 * 32 + lh * 8);

      // ---- O += P * V (V from regs) ----
#pragma unroll
      for (int df = 0; df < 8; ++df)
#pragma unroll
        for (int c2 = 0; c2 < 2; ++c2)
          o_acc[df] = __builtin_amdgcn_mfma_f32_16x16x32_bf16(ap[c2], vf[df][c2], o_acc[df], 0, 0, 0);

      __syncthreads();  // drains vmcnt -> next K tile staged; all waves done with buf
      buf ^= 1;
    }

    // epilogue: normalize and store bf16
    u16* op = O + (size_t)(b * S + q0 + w * 16 + lh * 4) * (size_t)(H * 128) + h * 128;
#pragma unroll
    for (int r = 0; r < 4; ++r) {
      float inv = 1.0f / l_run[r];
#pragma unroll
      for (int df = 0; df < 8; ++df)
        op[(size_t)r * (H * 128) + df * 16 + lr] = f2bf(o_acc[df][r] * inv);
    }
  }
}

extern "C" void kernel_launch(void* const* d_in, const int* in_sizes, int n_in, void* d_out,
                              int out_size, void* d_ws, size_t ws_size, hipStream_t stream) {
  const float* x = (const float*)d_in[0];
  const float* Wq = (const float*)d_in[1];
  const float* Wk = (const float*)d_in[2];
  const float* Wv = (const float*)d_in[3];
  const float* Wp = (const float*)d_in[4];
  const float* gain = (const float*)d_in[5];
  float* out = (float*)d_out;

  const int B = 2, S = 2048, D = 2048, H = 16, KH = 4;
  const int M = B * S;
  const int KVD = KH * 128;

  char* w = (char*)d_ws;
  u16* x_bf = (u16*)w;  w += (size_t)M * D * 2;
  u16* wq_bf = (u16*)w; w += (size_t)D * D * 2;
  u16* wk_bf = (u16*)w; w += (size_t)KVD * D * 2;
  u16* wv_bf = (u16*)w; w += (size_t)KVD * D * 2;
  u16* wp_bf = (u16*)w; w += (size_t)D * D * 2;
  u16* q_bf = (u16*)w;  w += (size_t)M * D * 2;
  u16* k_bf = (u16*)w;  w += (size_t)M * KVD * 2;
  u16* v_t = (u16*)w;   w += (size_t)M * KVD * 2;
  u16* ao_bf = (u16*)w; w += (size_t)M * D * 2;
  float* cosT = (float*)w; w += (size_t)S * 64 * 4;
  float* sinT = (float*)w; w += (size_t)S * 64 * 4;
  if ((size_t)(w - (char*)d_ws) > ws_size) return;

  k_cast_bf16<<<(M * D / 4 + 255) / 256, 256, 0, stream>>>(x, x_bf, M * D / 4);
  k_cast_bf16<<<(D * D / 4 + 255) / 256, 256, 0, stream>>>(Wq, wq_bf, D * D / 4);
  k_cast_bf16<<<(KVD * D / 4 + 255) / 256, 256, 0, stream>>>(Wk, wk_bf, KVD * D / 4);
  k_cast_bf16<<<(KVD * D / 4 + 255) / 256, 256, 0, stream>>>(Wv, wv_bf, KVD * D / 4);
  k_cast_bf16<<<(D * D / 4 + 255) / 256, 256, 0, stream>>>(Wp, wp_bf, D * D / 4);

  double scale = (double)S / 1024.0;
  double base = (S > 1024) ? 10000.0 * pow(scale, 128.0 / 126.0) : 10000.0;
  float l2b = (float)(log(base) / log(2.0));
  k_rope_tab<<<S * 64 / 256, 256, 0, stream>>>(cosT, sinT, l2b);

  dim3 blk(256);
  dim3 gq(D / 128, M / 128);
  k_gemm_bt<u16, false><<<gq, blk, 0, stream>>>(x_bf, wq_bf, q_bf, M, D, D);
  dim3 gkv(KVD / 128, M / 128);
  k_gemm_bt<u16, false><<<gkv, blk, 0, stream>>>(x_bf, wk_bf, k_bf, M, KVD, D);
  k_gemm_bt<u16, true><<<gkv, blk, 0, stream>>>(x_bf, wv_bf, v_t, M, KVD, D);

  k_rmsnorm_rope<<<(M * H) / 4, 256, 0, stream>>>(q_bf, cosT, sinT, gain, H, S);
  k_rmsnorm_rope<<<(M * KH) / 4, 256, 0, stream>>>(k_bf, cosT, sinT, nullptr, KH, S);

  dim3 ga(B * H, S / 128);  // 16 complementary pairs of 64-row q-tiles
  k_flash_attn<<<ga, blk, 0, stream>>>(q_bf, k_bf, v_t, ao_bf, S, H, KH, M);

  k_gemm_bt<float, false><<<gq, blk, 0, stream>>>(ao_bf, wp_bf, out, M, D, D);
}

// Round 3
// 381.499 us; speedup vs baseline: 1.4254x; 1.0775x over previous
//
#include <hip/hip_runtime.h>
#include <cmath>

typedef unsigned short u16;
typedef short v8s __attribute__((ext_vector_type(8)));
typedef float v4f __attribute__((ext_vector_type(4)));
typedef unsigned short v4u __attribute__((ext_vector_type(4)));
typedef unsigned int v2u __attribute__((ext_vector_type(2)));

__device__ __forceinline__ u16 f2bf(float f) {
  unsigned u = __builtin_bit_cast(unsigned, f);
  u += 0x7fffu + ((u >> 16) & 1u);
  return (u16)(u >> 16);
}
__device__ __forceinline__ float bf2f(u16 h) {
  unsigned u = ((unsigned)h) << 16;
  return __builtin_bit_cast(float, u);
}
__device__ __forceinline__ unsigned pk2(float a, float b) {
  return (unsigned)f2bf(a) | ((unsigned)f2bf(b) << 16);
}

// ---------------- cast fp32 -> bf16 (vectorized, G13) ----------------
__global__ void k_cast_bf16(const float* __restrict__ in, u16* __restrict__ out, int n4) {
  int i = blockIdx.x * blockDim.x + threadIdx.x;
  if (i >= n4) return;
  v4f v = ((const v4f*)in)[i];
  v4u o;
  o[0] = f2bf(v[0]); o[1] = f2bf(v[1]); o[2] = f2bf(v[2]); o[3] = f2bf(v[3]);
  ((v4u*)out)[i] = o;
}

// ---------------- RoPE cos/sin table [S][64] f32 ----------------
__global__ void k_rope_tab(float* __restrict__ cosT, float* __restrict__ sinT, float log2_base) {
  int idx = blockIdx.x * blockDim.x + threadIdx.x;
  int t = idx >> 6, i = idx & 63;
  float inv = exp2f(-(float)i * (1.0f / 64.0f) * log2_base);
  float fr = (float)t * inv;
  cosT[idx] = cosf(fr);
  sinT[idx] = sinf(fr);
}

// ------ per-head RMSNorm + RoPE + gain + output scale (in-place, bf16) -------
// oscale folds attention's log2(e)/sqrt(hd) into Q (VALU saved in attn loop)
__global__ void k_rmsnorm_rope(u16* __restrict__ qk, const float* __restrict__ cosT,
                               const float* __restrict__ sinT, const float* __restrict__ gain,
                               int H, int S, float oscale) {
  int row = blockIdx.x * 4 + (threadIdx.x >> 6);
  int l = threadIdx.x & 63;
  int h = row % H;
  int m = row / H;
  int s = m % S;
  u16* p = qk + (size_t)row * 128;
  float a = bf2f(p[l]), b = bf2f(p[64 + l]);
  float ss = a * a + b * b;
#pragma unroll
  for (int o = 32; o; o >>= 1) ss += __shfl_xor(ss, o, 64);
  float r = rsqrtf(ss * (1.0f / 128.0f) + 1.1920929e-7f);
  a *= r; b *= r;
  float c = cosT[s * 64 + l], sn = sinT[s * 64 + l];
  float o1 = a * c + b * sn;
  float o2 = b * c - a * sn;
  float g = oscale;
  if (gain != nullptr) g *= gain[h];
  p[l] = f2bf(o1 * g);
  p[64 + l] = f2bf(o2 * g);
}

// ---------------- bf16 GEMM: C[M,N] = A[M,K] * Bw[N,K]^T (m97 structure) ------
template <typename OUT_T, bool TRANS>
__global__ __launch_bounds__(256) void k_gemm_bt(const u16* __restrict__ A,
                                                 const u16* __restrict__ Bw,
                                                 OUT_T* __restrict__ C, int M, int N, int K) {
  __shared__ u16 sA[128 * 32];
  __shared__ u16 sB[128 * 32];
  const int tid = threadIdx.x;
  const int w = tid >> 6, l = tid & 63;
  const int lr = l & 15, lh = l >> 4;
  const int wr = w >> 1, wc = w & 1;
  const int row0 = blockIdx.y * 128, col0 = blockIdx.x * 128;
  v4f zz = {0.f, 0.f, 0.f, 0.f};
  v4f acc[4][4];
#pragma unroll
  for (int mi = 0; mi < 4; ++mi)
#pragma unroll
    for (int ni = 0; ni < 4; ++ni) acc[mi][ni] = zz;

  const int lrow = l >> 2;
  const int lcol = (l & 3) * 8;

  for (int k0 = 0; k0 < K; k0 += 32) {
#pragma unroll
    for (int i = 0; i < 2; ++i) {
      int c = i * 4 + w;
      const u16* srcA = A + (size_t)(row0 + c * 16 + lrow) * K + (k0 + lcol);
      const u16* srcB = Bw + (size_t)(col0 + c * 16 + lrow) * K + (k0 + lcol);
      __builtin_amdgcn_global_load_lds((const __attribute__((address_space(1))) void*)srcA,
                                       (__attribute__((address_space(3))) void*)(sA + c * 512),
                                       16, 0, 0);
      __builtin_amdgcn_global_load_lds((const __attribute__((address_space(1))) void*)srcB,
                                       (__attribute__((address_space(3))) void*)(sB + c * 512),
                                       16, 0, 0);
    }
    __syncthreads();
    v8s af[4], bfr[4];
#pragma unroll
    for (int mi = 0; mi < 4; ++mi)
      af[mi] = *(const v8s*)(sA + (wr * 64 + mi * 16 + lr) * 32 + lh * 8);
#pragma unroll
    for (int ni = 0; ni < 4; ++ni)
      bfr[ni] = *(const v8s*)(sB + (wc * 64 + ni * 16 + lr) * 32 + lh * 8);
#pragma unroll
    for (int mi = 0; mi < 4; ++mi)
#pragma unroll
      for (int ni = 0; ni < 4; ++ni)
        acc[mi][ni] = __builtin_amdgcn_mfma_f32_16x16x32_bf16(af[mi], bfr[ni], acc[mi][ni], 0, 0, 0);
    __syncthreads();
  }
#pragma unroll
  for (int mi = 0; mi < 4; ++mi) {
#pragma unroll
    for (int ni = 0; ni < 4; ++ni) {
      int row = row0 + wr * 64 + mi * 16 + lh * 4;
      int col = col0 + wc * 64 + ni * 16 + lr;
#pragma unroll
      for (int r = 0; r < 4; ++r) {
        float v = acc[mi][ni][r];
        if constexpr (TRANS) {
          if constexpr (sizeof(OUT_T) == 2) C[(size_t)col * M + row + r] = (OUT_T)f2bf(v);
          else                              C[(size_t)col * M + row + r] = (OUT_T)v;
        } else {
          if constexpr (sizeof(OUT_T) == 2) C[(size_t)(row + r) * N + col] = (OUT_T)f2bf(v);
          else                              C[(size_t)(row + r) * N + col] = (OUT_T)v;
        }
      }
    }
  }
}

// ---------------- causal GQA flash attention v3 ----------------
// Swapped QK^T: sv = mfma(K,Q) -> lane owns q=lr, 16 kv-values in-register.
// In-lane softmax (2 shfl), defer-max (T13), packed-P LDS round trip.
__global__ __launch_bounds__(256) void k_flash_attn(const u16* __restrict__ Q,
                                                    const u16* __restrict__ Kb,
                                                    const u16* __restrict__ Vt,
                                                    u16* __restrict__ O, int S, int H, int KH,
                                                    int Mtot) {
  const int bh = blockIdx.x;
  const int h = bh % H, b = bh / H;
  const int kvh = h / (H / KH);
  const int w = threadIdx.x >> 6, l = threadIdx.x & 63;
  const int lr = l & 15, lh = l >> 4;

  __shared__ alignas(16) char sK[2][16384];           // 64 kv-rows x 256B, swizzled
  __shared__ alignas(16) unsigned P_lds[4][16 * 36];  // per-wave packed P (row=q, 36 u32 stride)
  unsigned* prow = P_lds[w] + lr * 36;

  v4f zz = {0.f, 0.f, 0.f, 0.f};
  const int strideK = KH * 128;
  const int strideKB = strideK * 2;
  const char* KheadB = (const char*)Kb + 2 * ((size_t)b * S * strideK + (size_t)kvh * 128);
  const u16* Vbase = Vt + (size_t)(kvh * 128) * Mtot + (size_t)b * S;

  for (int pp = 0; pp < 2; ++pp) {
    const int qt = (pp == 0) ? (int)blockIdx.y : (S / 64 - 1 - (int)blockIdx.y);
    const int q0 = qt * 64;
    const int nt = qt + 1;
    const int qi = q0 + w * 16 + lr;  // this lane's q row

    // Q fragments in regs (pre-scaled by log2e/sqrt(hd) and gain)
    v8s qf[4];
    const u16* qp = Q + (size_t)(b * S + q0 + w * 16 + lr) * (size_t)(H * 128) + h * 128 + lh * 8;
#pragma unroll
    for (int c = 0; c < 4; ++c) qf[c] = *(const v8s*)(qp + c * 32);

    v4f o_acc[8];
#pragma unroll
    for (int df = 0; df < 8; ++df) o_acc[df] = zz;
    float m_run = -1e30f, l_run = 0.f;

    // prologue: stage K tile 0 into buf 0
    {
      const char* Kt = KheadB;
#pragma unroll
      for (int j = 0; j < 4; ++j) {
        int jj = w * 4 + j;
        int ci = jj * 64 + l;
        int r = ci >> 4;
        int bc = (ci & 15) << 4;
        const char* src = Kt + (size_t)r * strideKB + (bc ^ ((r & 15) << 4));
        __builtin_amdgcn_global_load_lds((const __attribute__((address_space(1))) void*)src,
                                         (__attribute__((address_space(3))) void*)(sK[0] + jj * 1024),
                                         16, 0, 0);
      }
    }
    __syncthreads();

    int buf = 0;
    for (int t = 0; t < nt; ++t) {
      const int kv0 = t * 64;
      const bool lastTile = (t == nt - 1);
      const char* sKb = sK[buf];

      // ---- QK^T swapped: sv[nf] rows = kv, cols = q ----
      v4f sv[4];
#pragma unroll
      for (int nf = 0; nf < 4; ++nf) {
        v4f a_ = zz;
        const int r = nf * 16 + lr;
#pragma unroll
        for (int c = 0; c < 4; ++c) {
          v8s kf = *(const v8s*)(sKb + r * 256 + ((lh * 16 + c * 64) ^ (lr << 4)));
          a_ = __builtin_amdgcn_mfma_f32_16x16x32_bf16(kf, qf[c], a_, 0, 0, 0);
        }
        sv[nf] = a_;
      }

      // ---- prefetch V fragments to regs ----
      v8s vf[8][2];
#pragma unroll
      for (int df = 0; df < 8; ++df) {
        const u16* vp = Vbase + (size_t)(df * 16 + lr) * Mtot + kv0 + lh * 8;
#pragma unroll
        for (int c2 = 0; c2 < 2; ++c2) vf[df][c2] = *(const v8s*)(vp + c2 * 32);
      }

      // ---- stage next K tile ----
      if (t + 1 < nt) {
        const char* Kt = KheadB + (size_t)(kv0 + 64) * strideKB;
        char* dst = (char*)sK[buf ^ 1];
#pragma unroll
        for (int j = 0; j < 4; ++j) {
          int jj = w * 4 + j;
          int ci = jj * 64 + l;
          int r = ci >> 4;
          int bc = (ci & 15) << 4;
          const char* src = Kt + (size_t)r * strideKB + (bc ^ ((r & 15) << 4));
          __builtin_amdgcn_global_load_lds((const __attribute__((address_space(1))) void*)src,
                                           (__attribute__((address_space(3))) void*)(dst + jj * 1024),
                                           16, 0, 0);
        }
      }

      // ---- in-lane online softmax (lane owns q=lr; kv = kv0+16nf+4lh+r) ----
      if (lastTile) {
#pragma unroll
        for (int nf = 0; nf < 4; ++nf)
#pragma unroll
          for (int r = 0; r < 4; ++r)
            if (kv0 + nf * 16 + lh * 4 + r > qi) sv[nf][r] = -1e30f;
      }
      float pmax = -1e30f;
#pragma unroll
      for (int nf = 0; nf < 4; ++nf)
#pragma unroll
        for (int r = 0; r < 4; ++r) pmax = fmaxf(pmax, sv[nf][r]);
      pmax = fmaxf(pmax, __shfl_xor(pmax, 16, 64));
      pmax = fmaxf(pmax, __shfl_xor(pmax, 32, 64));
      if (!__all(pmax - m_run <= 8.0f)) {  // T13 defer-max
        float mnew = fmaxf(m_run, pmax);
        float corr = exp2f(m_run - mnew);
        l_run *= corr;
        m_run = mnew;
        float corrq[4];
#pragma unroll
        for (int r = 0; r < 4; ++r) corrq[r] = __shfl(corr, lh * 4 + r, 16);
#pragma unroll
        for (int df = 0; df < 8; ++df)
#pragma unroll
          for (int r = 0; r < 4; ++r) o_acc[df][r] *= corrq[r];
      }
      float rsum = 0.f;
#pragma unroll
      for (int nf = 0; nf < 4; ++nf)
#pragma unroll
        for (int r = 0; r < 4; ++r) {
          float pv = exp2f(sv[nf][r] - m_run);
          sv[nf][r] = pv;
          rsum += pv;
        }
      rsum += __shfl_xor(rsum, 16, 64);
      rsum += __shfl_xor(rsum, 32, 64);
      l_run += rsum;

      // ---- pack P to bf16 pairs, 4x ds_write_b64, reload as A-frags ----
#pragma unroll
      for (int nf = 0; nf < 4; ++nf) {
        v2u pw;
        pw[0] = pk2(sv[nf][0], sv[nf][1]);
        pw[1] = pk2(sv[nf][2], sv[nf][3]);
        *(v2u*)(prow + nf * 8 + lh * 2) = pw;
      }
      asm volatile("s_waitcnt lgkmcnt(0)" ::: "memory");
      __builtin_amdgcn_sched_barrier(0);  // rule 18
      v8s ap[2];
#pragma unroll
      for (int c2 = 0; c2 < 2; ++c2) ap[c2] = *(const v8s*)(prow + c2 * 16 + lh * 4);

      // ---- O += P * V ----
#pragma unroll
      for (int df = 0; df < 8; ++df)
#pragma unroll
        for (int c2 = 0; c2 < 2; ++c2)
          o_acc[df] = __builtin_amdgcn_mfma_f32_16x16x32_bf16(ap[c2], vf[df][c2], o_acc[df], 0, 0, 0);

      __syncthreads();
      buf ^= 1;
    }

    // epilogue: normalize (broadcast 1/l per q-row) and store bf16
    float rl = 1.0f / l_run;
    float invq[4];
#pragma unroll
    for (int r = 0; r < 4; ++r) invq[r] = __shfl(rl, lh * 4 + r, 16);
    u16* op = O + (size_t)(b * S + q0 + w * 16 + lh * 4) * (size_t)(H * 128) + h * 128;
#pragma unroll
    for (int r = 0; r < 4; ++r)
#pragma unroll
      for (int df = 0; df < 8; ++df)
        op[(size_t)r * (H * 128) + df * 16 + lr] = f2bf(o_acc[df][r] * invq[r]);
  }
}

extern "C" void kernel_launch(void* const* d_in, const int* in_sizes, int n_in, void* d_out,
                              int out_size, void* d_ws, size_t ws_size, hipStream_t stream) {
  const float* x = (const float*)d_in[0];
  const float* Wq = (const float*)d_in[1];
  const float* Wk = (const float*)d_in[2];
  const float* Wv = (const float*)d_in[3];
  const float* Wp = (const float*)d_in[4];
  const float* gain = (const float*)d_in[5];
  float* out = (float*)d_out;

  const int B = 2, S = 2048, D = 2048, H = 16, KH = 4;
  const int M = B * S;
  const int KVD = KH * 128;

  char* w = (char*)d_ws;
  u16* x_bf = (u16*)w;  w += (size_t)M * D * 2;
  u16* wq_bf = (u16*)w; w += (size_t)D * D * 2;
  u16* wk_bf = (u16*)w; w += (size_t)KVD * D * 2;
  u16* wv_bf = (u16*)w; w += (size_t)KVD * D * 2;
  u16* wp_bf = (u16*)w; w += (size_t)D * D * 2;
  u16* q_bf = (u16*)w;  w += (size_t)M * D * 2;
  u16* k_bf = (u16*)w;  w += (size_t)M * KVD * 2;
  u16* v_t = (u16*)w;   w += (size_t)M * KVD * 2;
  u16* ao_bf = (u16*)w; w += (size_t)M * D * 2;
  float* cosT = (float*)w; w += (size_t)S * 64 * 4;
  float* sinT = (float*)w; w += (size_t)S * 64 * 4;
  if ((size_t)(w - (char*)d_ws) > ws_size) return;

  k_cast_bf16<<<(M * D / 4 + 255) / 256, 256, 0, stream>>>(x, x_bf, M * D / 4);
  k_cast_bf16<<<(D * D / 4 + 255) / 256, 256, 0, stream>>>(Wq, wq_bf, D * D / 4);
  k_cast_bf16<<<(KVD * D / 4 + 255) / 256, 256, 0, stream>>>(Wk, wk_bf, KVD * D / 4);
  k_cast_bf16<<<(KVD * D / 4 + 255) / 256, 256, 0, stream>>>(Wv, wv_bf, KVD * D / 4);
  k_cast_bf16<<<(D * D / 4 + 255) / 256, 256, 0, stream>>>(Wp, wp_bf, D * D / 4);

  double scale = (double)S / 1024.0;
  double base = (S > 1024) ? 10000.0 * pow(scale, 128.0 / 126.0) : 10000.0;
  float l2b = (float)(log(base) / log(2.0));
  k_rope_tab<<<S * 64 / 256, 256, 0, stream>>>(cosT, sinT, l2b);

  dim3 blk(256);
  dim3 gq(D / 128, M / 128);
  k_gemm_bt<u16, false><<<gq, blk, 0, stream>>>(x_bf, wq_bf, q_bf, M, D, D);
  dim3 gkv(KVD / 128, M / 128);
  k_gemm_bt<u16, false><<<gkv, blk, 0, stream>>>(x_bf, wk_bf, k_bf, M, KVD, D);
  k_gemm_bt<u16, true><<<gkv, blk, 0, stream>>>(x_bf, wv_bf, v_t, M, KVD, D);

  float qscale = 1.4426950408889634f / sqrtf(128.0f);  // log2(e)/sqrt(hd), folded into Q
  k_rmsnorm_rope<<<(M * H) / 4, 256, 0, stream>>>(q_bf, cosT, sinT, gain, H, S, qscale);
  k_rmsnorm_rope<<<(M * KH) / 4, 256, 0, stream>>>(k_bf, cosT, sinT, nullptr, KH, S, 1.0f);

  dim3 ga(B * H, S / 128);
  k_flash_attn<<<ga, blk, 0, stream>>>(q_bf, k_bf, v_t, ao_bf, S, H, KH, M);

  k_gemm_bt<float, false><<<gq, blk, 0, stream>>>(ao_bf, wp_bf, out, M, D, D);
}

// Round 4
// 311.196 us; speedup vs baseline: 1.7474x; 1.2259x over previous
//
#include <hip/hip_runtime.h>
#include <cmath>

typedef unsigned short u16;
typedef short v8s __attribute__((ext_vector_type(8)));
typedef float v4f __attribute__((ext_vector_type(4)));
typedef unsigned short v4u __attribute__((ext_vector_type(4)));
typedef unsigned int v2u __attribute__((ext_vector_type(2)));

__device__ __forceinline__ u16 f2bf(float f) {
  unsigned u = __builtin_bit_cast(unsigned, f);
  u += 0x7fffu + ((u >> 16) & 1u);
  return (u16)(u >> 16);
}
__device__ __forceinline__ float bf2f(u16 h) {
  unsigned u = ((unsigned)h) << 16;
  return __builtin_bit_cast(float, u);
}
__device__ __forceinline__ unsigned pk2(float a, float b) {
  return (unsigned)f2bf(a) | ((unsigned)f2bf(b) << 16);
}

// ---------------- cast fp32 -> bf16 (vectorized, G13) ----------------
__global__ void k_cast_bf16(const float* __restrict__ in, u16* __restrict__ out, int n4) {
  int i = blockIdx.x * blockDim.x + threadIdx.x;
  if (i >= n4) return;
  v4f v = ((const v4f*)in)[i];
  v4u o;
  o[0] = f2bf(v[0]); o[1] = f2bf(v[1]); o[2] = f2bf(v[2]); o[3] = f2bf(v[3]);
  ((v4u*)out)[i] = o;
}

// ---------------- fused cast of the 4 weight tensors ----------------
__global__ void k_cast_w(const float* __restrict__ a, const float* __restrict__ b,
                         const float* __restrict__ c, const float* __restrict__ d,
                         u16* __restrict__ oa, u16* __restrict__ ob, u16* __restrict__ oc,
                         u16* __restrict__ od, int na4, int nb4, int nc4, int nd4) {
  int j = blockIdx.x * blockDim.x + threadIdx.x;
  const float* src;
  u16* dst;
  if (j < na4) { src = a; dst = oa; }
  else {
    j -= na4;
    if (j < nb4) { src = b; dst = ob; }
    else {
      j -= nb4;
      if (j < nc4) { src = c; dst = oc; }
      else {
        j -= nc4;
        if (j >= nd4) return;
        src = d; dst = od;
      }
    }
  }
  v4f v = ((const v4f*)src)[j];
  v4u o;
  o[0] = f2bf(v[0]); o[1] = f2bf(v[1]); o[2] = f2bf(v[2]); o[3] = f2bf(v[3]);
  ((v4u*)dst)[j] = o;
}

// ---------------- RoPE cos/sin table [S][64] f32 ----------------
__global__ void k_rope_tab(float* __restrict__ cosT, float* __restrict__ sinT, float log2_base) {
  int idx = blockIdx.x * blockDim.x + threadIdx.x;
  int t = idx >> 6, i = idx & 63;
  float inv = exp2f(-(float)i * (1.0f / 64.0f) * log2_base);
  float fr = (float)t * inv;
  cosT[idx] = cosf(fr);
  sinT[idx] = sinf(fr);
}

// ------ per-head RMSNorm + RoPE + gain + output scale (in-place, bf16) -------
__global__ void k_rmsnorm_rope(u16* __restrict__ qk, const float* __restrict__ cosT,
                               const float* __restrict__ sinT, const float* __restrict__ gain,
                               int H, int S, float oscale) {
  int row = blockIdx.x * 4 + (threadIdx.x >> 6);
  int l = threadIdx.x & 63;
  int h = row % H;
  int m = row / H;
  int s = m % S;
  u16* p = qk + (size_t)row * 128;
  float a = bf2f(p[l]), b = bf2f(p[64 + l]);
  float ss = a * a + b * b;
#pragma unroll
  for (int o = 32; o; o >>= 1) ss += __shfl_xor(ss, o, 64);
  float r = rsqrtf(ss * (1.0f / 128.0f) + 1.1920929e-7f);
  a *= r; b *= r;
  float c = cosT[s * 64 + l], sn = sinT[s * 64 + l];
  float o1 = a * c + b * sn;
  float o2 = b * c - a * sn;
  float g = oscale;
  if (gain != nullptr) g *= gain[h];
  p[l] = f2bf(o1 * g);
  p[64 + l] = f2bf(o2 * g);
}

// -------- fused QKV GEMM: [M,2048]x[3072,2048]^T -> q/k/v_t (m97 + T1) -------
__global__ __launch_bounds__(256) void k_gemm_qkv(const u16* __restrict__ A,
                                                  const u16* __restrict__ Bw,
                                                  u16* __restrict__ q_o, u16* __restrict__ k_o,
                                                  u16* __restrict__ v_o, int M, int K) {
  __shared__ u16 sA[128 * 32];
  __shared__ u16 sB[128 * 32];
  const int tid = threadIdx.x;
  const int w = tid >> 6, l = tid & 63;
  const int lr = l & 15, lh = l >> 4;
  const int wr = w >> 1, wc = w & 1;
  // T1 bijective XCD swizzle (nwg = 768, %8 == 0)
  const int nwg = gridDim.x * gridDim.y;
  const int bid = blockIdx.y * gridDim.x + blockIdx.x;
  const int cpx = nwg >> 3;
  const int swz = (bid & 7) * cpx + (bid >> 3);
  const int row0 = (swz / gridDim.x) * 128, col0 = (swz % gridDim.x) * 128;
  v4f zz = {0.f, 0.f, 0.f, 0.f};
  v4f acc[4][4];
#pragma unroll
  for (int mi = 0; mi < 4; ++mi)
#pragma unroll
    for (int ni = 0; ni < 4; ++ni) acc[mi][ni] = zz;

  const int lrow = l >> 2;
  const int lcol = (l & 3) * 8;

  for (int k0 = 0; k0 < K; k0 += 32) {
#pragma unroll
    for (int i = 0; i < 2; ++i) {
      int c = i * 4 + w;
      const u16* srcA = A + (size_t)(row0 + c * 16 + lrow) * K + (k0 + lcol);
      const u16* srcB = Bw + (size_t)(col0 + c * 16 + lrow) * K + (k0 + lcol);
      __builtin_amdgcn_global_load_lds((const __attribute__((address_space(1))) void*)srcA,
                                       (__attribute__((address_space(3))) void*)(sA + c * 512),
                                       16, 0, 0);
      __builtin_amdgcn_global_load_lds((const __attribute__((address_space(1))) void*)srcB,
                                       (__attribute__((address_space(3))) void*)(sB + c * 512),
                                       16, 0, 0);
    }
    __syncthreads();
    v8s af[4], bfr[4];
#pragma unroll
    for (int mi = 0; mi < 4; ++mi)
      af[mi] = *(const v8s*)(sA + (wr * 64 + mi * 16 + lr) * 32 + lh * 8);
#pragma unroll
    for (int ni = 0; ni < 4; ++ni)
      bfr[ni] = *(const v8s*)(sB + (wc * 64 + ni * 16 + lr) * 32 + lh * 8);
#pragma unroll
    for (int mi = 0; mi < 4; ++mi)
#pragma unroll
      for (int ni = 0; ni < 4; ++ni)
        acc[mi][ni] = __builtin_amdgcn_mfma_f32_16x16x32_bf16(af[mi], bfr[ni], acc[mi][ni], 0, 0, 0);
    __syncthreads();
  }
  // region routing (block-uniform: col0 multiple of 128; bounds 2048/2560 aligned)
  u16* outp;
  int ldo = 0, cb;
  bool tr = false;
  if (col0 < 2048) { outp = q_o; ldo = 2048; cb = col0; }
  else if (col0 < 2560) { outp = k_o; ldo = 512; cb = col0 - 2048; }
  else { outp = v_o; tr = true; cb = col0 - 2560; }
#pragma unroll
  for (int mi = 0; mi < 4; ++mi) {
#pragma unroll
    for (int ni = 0; ni < 4; ++ni) {
      int row = row0 + wr * 64 + mi * 16 + lh * 4;
      int col = cb + wc * 64 + ni * 16 + lr;
#pragma unroll
      for (int r = 0; r < 4; ++r) {
        u16 bv = f2bf(acc[mi][ni][r]);
        if (tr) outp[(size_t)col * M + row + r] = bv;
        else    outp[(size_t)(row + r) * ldo + col] = bv;
      }
    }
  }
}

// ---------------- out-proj GEMM: C[M,N] = A[M,K] * Bw[N,K]^T (m97 + T1) ------
__global__ __launch_bounds__(256) void k_gemm_bt(const u16* __restrict__ A,
                                                 const u16* __restrict__ Bw,
                                                 float* __restrict__ C, int M, int N, int K) {
  __shared__ u16 sA[128 * 32];
  __shared__ u16 sB[128 * 32];
  const int tid = threadIdx.x;
  const int w = tid >> 6, l = tid & 63;
  const int lr = l & 15, lh = l >> 4;
  const int wr = w >> 1, wc = w & 1;
  const int nwg = gridDim.x * gridDim.y;
  const int bid = blockIdx.y * gridDim.x + blockIdx.x;
  const int cpx = nwg >> 3;
  const int swz = (bid & 7) * cpx + (bid >> 3);
  const int row0 = (swz / gridDim.x) * 128, col0 = (swz % gridDim.x) * 128;
  v4f zz = {0.f, 0.f, 0.f, 0.f};
  v4f acc[4][4];
#pragma unroll
  for (int mi = 0; mi < 4; ++mi)
#pragma unroll
    for (int ni = 0; ni < 4; ++ni) acc[mi][ni] = zz;

  const int lrow = l >> 2;
  const int lcol = (l & 3) * 8;

  for (int k0 = 0; k0 < K; k0 += 32) {
#pragma unroll
    for (int i = 0; i < 2; ++i) {
      int c = i * 4 + w;
      const u16* srcA = A + (size_t)(row0 + c * 16 + lrow) * K + (k0 + lcol);
      const u16* srcB = Bw + (size_t)(col0 + c * 16 + lrow) * K + (k0 + lcol);
      __builtin_amdgcn_global_load_lds((const __attribute__((address_space(1))) void*)srcA,
                                       (__attribute__((address_space(3))) void*)(sA + c * 512),
                                       16, 0, 0);
      __builtin_amdgcn_global_load_lds((const __attribute__((address_space(1))) void*)srcB,
                                       (__attribute__((address_space(3))) void*)(sB + c * 512),
                                       16, 0, 0);
    }
    __syncthreads();
    v8s af[4], bfr[4];
#pragma unroll
    for (int mi = 0; mi < 4; ++mi)
      af[mi] = *(const v8s*)(sA + (wr * 64 + mi * 16 + lr) * 32 + lh * 8);
#pragma unroll
    for (int ni = 0; ni < 4; ++ni)
      bfr[ni] = *(const v8s*)(sB + (wc * 64 + ni * 16 + lr) * 32 + lh * 8);
#pragma unroll
    for (int mi = 0; mi < 4; ++mi)
#pragma unroll
      for (int ni = 0; ni < 4; ++ni)
        acc[mi][ni] = __builtin_amdgcn_mfma_f32_16x16x32_bf16(af[mi], bfr[ni], acc[mi][ni], 0, 0, 0);
    __syncthreads();
  }
#pragma unroll
  for (int mi = 0; mi < 4; ++mi) {
#pragma unroll
    for (int ni = 0; ni < 4; ++ni) {
      int row = row0 + wr * 64 + mi * 16 + lh * 4;
      int col = col0 + wc * 64 + ni * 16 + lr;
#pragma unroll
      for (int r = 0; r < 4; ++r) C[(size_t)(row + r) * N + col] = acc[mi][ni][r];
    }
  }
}

// ---------------- causal GQA flash attention v4 ----------------
// Swapped QK^T, in-lane softmax, defer-max, XOR-swizzled packed-P LDS.
__global__ __launch_bounds__(256) void k_flash_attn(const u16* __restrict__ Q,
                                                    const u16* __restrict__ Kb,
                                                    const u16* __restrict__ Vt,
                                                    u16* __restrict__ O, int S, int H, int KH,
                                                    int Mtot) {
  const int bh = blockIdx.x;
  const int h = bh % H, b = bh / H;
  const int kvh = h / (H / KH);
  const int w = threadIdx.x >> 6, l = threadIdx.x & 63;
  const int lr = l & 15, lh = l >> 4;

  __shared__ alignas(16) char sK[2][16384];           // 64 kv-rows x 256B, swizzled
  __shared__ alignas(16) unsigned P_lds[4][16 * 32];  // per-wave packed P, XOR-swizzled
  unsigned* prow = P_lds[w] + lr * 32;
  const int xr = (lr & 7) << 2;  // per-row word-XOR key (G21 both-sides involution)

  v4f zz = {0.f, 0.f, 0.f, 0.f};
  const int strideK = KH * 128;
  const int strideKB = strideK * 2;
  const char* KheadB = (const char*)Kb + 2 * ((size_t)b * S * strideK + (size_t)kvh * 128);
  const u16* Vbase = Vt + (size_t)(kvh * 128) * Mtot + (size_t)b * S;

  for (int pp = 0; pp < 2; ++pp) {
    const int qt = (pp == 0) ? (int)blockIdx.y : (S / 64 - 1 - (int)blockIdx.y);
    const int q0 = qt * 64;
    const int nt = qt + 1;
    const int qi = q0 + w * 16 + lr;

    v8s qf[4];
    const u16* qp = Q + (size_t)(b * S + q0 + w * 16 + lr) * (size_t)(H * 128) + h * 128 + lh * 8;
#pragma unroll
    for (int c = 0; c < 4; ++c) qf[c] = *(const v8s*)(qp + c * 32);

    v4f o_acc[8];
#pragma unroll
    for (int df = 0; df < 8; ++df) o_acc[df] = zz;
    float m_run = -1e30f, l_run = 0.f;

    {
      const char* Kt = KheadB;
#pragma unroll
      for (int j = 0; j < 4; ++j) {
        int jj = w * 4 + j;
        int ci = jj * 64 + l;
        int r = ci >> 4;
        int bc = (ci & 15) << 4;
        const char* src = Kt + (size_t)r * strideKB + (bc ^ ((r & 15) << 4));
        __builtin_amdgcn_global_load_lds((const __attribute__((address_space(1))) void*)src,
                                         (__attribute__((address_space(3))) void*)(sK[0] + jj * 1024),
                                         16, 0, 0);
      }
    }
    __syncthreads();

    int buf = 0;
    for (int t = 0; t < nt; ++t) {
      const int kv0 = t * 64;
      const bool lastTile = (t == nt - 1);
      const char* sKb = sK[buf];

      v4f sv[4];
#pragma unroll
      for (int nf = 0; nf < 4; ++nf) {
        v4f a_ = zz;
        const int r = nf * 16 + lr;
#pragma unroll
        for (int c = 0; c < 4; ++c) {
          v8s kf = *(const v8s*)(sKb + r * 256 + ((lh * 16 + c * 64) ^ (lr << 4)));
          a_ = __builtin_amdgcn_mfma_f32_16x16x32_bf16(kf, qf[c], a_, 0, 0, 0);
        }
        sv[nf] = a_;
      }

      v8s vf[8][2];
#pragma unroll
      for (int df = 0; df < 8; ++df) {
        const u16* vp = Vbase + (size_t)(df * 16 + lr) * Mtot + kv0 + lh * 8;
#pragma unroll
        for (int c2 = 0; c2 < 2; ++c2) vf[df][c2] = *(const v8s*)(vp + c2 * 32);
      }

      if (t + 1 < nt) {
        const char* Kt = KheadB + (size_t)(kv0 + 64) * strideKB;
        char* dst = (char*)sK[buf ^ 1];
#pragma unroll
        for (int j = 0; j < 4; ++j) {
          int jj = w * 4 + j;
          int ci = jj * 64 + l;
          int r = ci >> 4;
          int bc = (ci & 15) << 4;
          const char* src = Kt + (size_t)r * strideKB + (bc ^ ((r & 15) << 4));
          __builtin_amdgcn_global_load_lds((const __attribute__((address_space(1))) void*)src,
                                           (__attribute__((address_space(3))) void*)(dst + jj * 1024),
                                           16, 0, 0);
        }
      }

      if (lastTile) {
#pragma unroll
        for (int nf = 0; nf < 4; ++nf)
#pragma unroll
          for (int r = 0; r < 4; ++r)
            if (kv0 + nf * 16 + lh * 4 + r > qi) sv[nf][r] = -1e30f;
      }
      float pmax = -1e30f;
#pragma unroll
      for (int nf = 0; nf < 4; ++nf)
#pragma unroll
        for (int r = 0; r < 4; ++r) pmax = fmaxf(pmax, sv[nf][r]);
      pmax = fmaxf(pmax, __shfl_xor(pmax, 16, 64));
      pmax = fmaxf(pmax, __shfl_xor(pmax, 32, 64));
      if (!__all(pmax - m_run <= 8.0f)) {  // T13 defer-max
        float mnew = fmaxf(m_run, pmax);
        float corr = exp2f(m_run - mnew);
        l_run *= corr;
        m_run = mnew;
        float corrq[4];
#pragma unroll
        for (int r = 0; r < 4; ++r) corrq[r] = __shfl(corr, lh * 4 + r, 16);
#pragma unroll
        for (int df = 0; df < 8; ++df)
#pragma unroll
          for (int r = 0; r < 4; ++r) o_acc[df][r] *= corrq[r];
      }
      float rsum = 0.f;
#pragma unroll
      for (int nf = 0; nf < 4; ++nf)
#pragma unroll
        for (int r = 0; r < 4; ++r) {
          float pv = exp2f(sv[nf][r] - m_run);
          sv[nf][r] = pv;
          rsum += pv;
        }
      rsum += __shfl_xor(rsum, 16, 64);
      rsum += __shfl_xor(rsum, 32, 64);
      l_run += rsum;

#pragma unroll
      for (int nf = 0; nf < 4; ++nf) {
        v2u pw;
        pw[0] = pk2(sv[nf][0], sv[nf][1]);
        pw[1] = pk2(sv[nf][2], sv[nf][3]);
        *(v2u*)(prow + ((nf * 8 + lh * 2) ^ xr)) = pw;
      }
      asm volatile("s_waitcnt lgkmcnt(0)" ::: "memory");
      __builtin_amdgcn_sched_barrier(0);  // rule 18
      v8s ap[2];
#pragma unroll
      for (int c2 = 0; c2 < 2; ++c2) ap[c2] = *(const v8s*)(prow + ((c2 * 16 + lh * 4) ^ xr));

#pragma unroll
      for (int df = 0; df < 8; ++df)
#pragma unroll
        for (int c2 = 0; c2 < 2; ++c2)
          o_acc[df] = __builtin_amdgcn_mfma_f32_16x16x32_bf16(ap[c2], vf[df][c2], o_acc[df], 0, 0, 0);

      __syncthreads();
      buf ^= 1;
    }

    float rl = 1.0f / l_run;
    float invq[4];
#pragma unroll
    for (int r = 0; r < 4; ++r) invq[r] = __shfl(rl, lh * 4 + r, 16);
    u16* op = O + (size_t)(b * S + q0 + w * 16 + lh * 4) * (size_t)(H * 128) + h * 128;
#pragma unroll
    for (int r = 0; r < 4; ++r)
#pragma unroll
      for (int df = 0; df < 8; ++df)
        op[(size_t)r * (H * 128) + df * 16 + lr] = f2bf(o_acc[df][r] * invq[r]);
  }
}

extern "C" void kernel_launch(void* const* d_in, const int* in_sizes, int n_in, void* d_out,
                              int out_size, void* d_ws, size_t ws_size, hipStream_t stream) {
  const float* x = (const float*)d_in[0];
  const float* Wq = (const float*)d_in[1];
  const float* Wk = (const float*)d_in[2];
  const float* Wv = (const float*)d_in[3];
  const float* Wp = (const float*)d_in[4];
  const float* gain = (const float*)d_in[5];
  float* out = (float*)d_out;

  const int B = 2, S = 2048, D = 2048, H = 16, KH = 4;
  const int M = B * S;
  const int KVD = KH * 128;
  const int NQKV = D + 2 * KVD;  // 3072

  char* w = (char*)d_ws;
  u16* x_bf = (u16*)w;   w += (size_t)M * D * 2;
  u16* wqkv = (u16*)w;   w += (size_t)NQKV * D * 2;
  u16* wp_bf = (u16*)w;  w += (size_t)D * D * 2;
  u16* q_bf = (u16*)w;   w += (size_t)M * D * 2;
  u16* k_bf = (u16*)w;   w += (size_t)M * KVD * 2;
  u16* v_t = (u16*)w;    w += (size_t)M * KVD * 2;
  u16* ao_bf = (u16*)w;  w += (size_t)M * D * 2;
  float* cosT = (float*)w; w += (size_t)S * 64 * 4;
  float* sinT = (float*)w; w += (size_t)S * 64 * 4;
  if ((size_t)(w - (char*)d_ws) > ws_size) return;

  // casts: x, then all weights fused (Wq/Wk/Wv into concatenated wqkv rows)
  k_cast_bf16<<<(M * D / 4 + 255) / 256, 256, 0, stream>>>(x, x_bf, M * D / 4);
  {
    int na4 = D * D / 4, nb4 = KVD * D / 4, nc4 = KVD * D / 4, nd4 = D * D / 4;
    int tot = na4 + nb4 + nc4 + nd4;
    k_cast_w<<<(tot + 255) / 256, 256, 0, stream>>>(
        Wq, Wk, Wv, Wp, wqkv, wqkv + (size_t)D * D, wqkv + (size_t)(D + KVD) * D, wp_bf,
        na4, nb4, nc4, nd4);
  }

  double scale = (double)S / 1024.0;
  double base = (S > 1024) ? 10000.0 * pow(scale, 128.0 / 126.0) : 10000.0;
  float l2b = (float)(log(base) / log(2.0));
  k_rope_tab<<<S * 64 / 256, 256, 0, stream>>>(cosT, sinT, l2b);

  dim3 blk(256);
  dim3 gqkv(NQKV / 128, M / 128);  // 24 x 32 = 768 blocks
  k_gemm_qkv<<<gqkv, blk, 0, stream>>>(x_bf, wqkv, q_bf, k_bf, v_t, M, D);

  float qscale = 1.4426950408889634f / sqrtf(128.0f);  // log2(e)/sqrt(hd)
  k_rmsnorm_rope<<<(M * H) / 4, 256, 0, stream>>>(q_bf, cosT, sinT, gain, H, S, qscale);
  k_rmsnorm_rope<<<(M * KH) / 4, 256, 0, stream>>>(k_bf, cosT, sinT, nullptr, KH, S, 1.0f);

  dim3 ga(B * H, S / 128);
  k_flash_attn<<<ga, blk, 0, stream>>>(q_bf, k_bf, v_t, ao_bf, S, H, KH, M);

  dim3 gp(D / 128, M / 128);  // 16 x 32 = 512 blocks
  k_gemm_bt<<<gp, blk, 0, stream>>>(ao_bf, wp_bf, out, M, D, D);
}